// Round 13
// baseline (440.231 us; speedup 1.0000x reference)
//
#include <hip/hip_runtime.h>

// 3x3 PCF soft-shadow — 3-pass, every HBM access streaming; permutations via LDS radix hops.
// vis[i] = (1/9) * sum_{ii,jj} sigmoid((zbuf[b, clip(y+ii), clip(x+jj)] - (depth_z[i]-BIAS)) * 1000)
//
// R12 isolated the last random-line wall: P3's vis gather (pidx->slab) = 310 MB
// FETCH / 94 us per dispatch (one 64B line per 4B probe, no reuse across the
// kernel-boundary L2 invalidate). Fix: invert the permutation the same way the
// forward direction is done — LDS-staged radix hop with full-line bursts:
//   P1: bin px into (batch, 64x64 zbuf tile); record = il(20)|xl(6)|yl(6) +
//       depth (8B). LDS histogram+scan+sort, burst runs padded to 8 recs=64B
//       (pad depth=+inf). No pidx. 8192 px/block (full CU occupancy).
//   P2: per bin: stage 66x66 tile in LDS (coalesced, once), depth from record
//       (NO scattered reads at all), compute vis, then LDS-bucket (il,vis)
//       pairs by il-chunk (il>>14) and burst full-line runs into per-chunk
//       pair lists. Slab stays clean -> no writeback.
//   P3: per 16K-px chunk: read pair list COALESCED, scatter into 64 KB LDS
//       window, write out coalesced. Window sentinel-init; missing px
//       (CAP/CAP3 overflow, ~1e-6) recomputed exactly from zbuf.

#define SHARPNESS 1000.0f
#define BIAS 0.008f
#define S2LOG2E 1442.6950408889634f    // 1000 * log2(e)

#define S_IMG   2048
#define NBATCH  8
#define HWK     (1 << 20)
#define TSH     6                      // 64x64 zbuf tiles
#define TPS     32
#define BPB     (TPS * TPS)            // 1024 bins per batch
#define CAP     1664                   // padded-run bin cap (+4.7 sigma; SENT covers rest)
#define RPT     7                      // ceil(CAP/256)
#define STW     66                     // staged tile width (64 + halo)
#define PXB     8192                   // pixels per P1 block
#define P1T     1024
#define PPT     (PXB / P1T)            // 8 px/thread
#define P1B     (HWK / PXB)            // 128 P1 blocks per batch
#define CHSH    14                     // il-chunk shift: 16K px chunks
#define NCH     (HWK >> CHSH)          // 64 chunks per batch
#define CHPX    (1 << CHSH)            // 16384
#define CAP3    21248                  // pair-list cap per chunk (+8.7 sigma)
#define SENT    0xFFFFFFFFu

typedef int      i4v __attribute__((ext_vector_type(4)));
typedef float    f2v __attribute__((ext_vector_type(2)));
typedef float    f4v __attribute__((ext_vector_type(4)));
typedef unsigned u2v __attribute__((ext_vector_type(2)));

__device__ __forceinline__ float sigf(float bb, float a) {
    const float t = (a - bb) * S2LOG2E;            // keep 2-op form: bit-stable
    return __builtin_amdgcn_rcpf(1.0f + exp2f(t));
}

// ---------------- Pass 1: LDS-sorted binning, burst full-line writes ----------------
__global__ __launch_bounds__(P1T, 4) void p1_bin(
    const int* __restrict__ xy_raw, const float* __restrict__ depth,
    u2v* __restrict__ slab, unsigned* __restrict__ gcur, int b0)
{
    __shared__ u2v      srec[PXB];     // 64 KB bin-sorted records
    __shared__ unsigned scn[BPB];      // hist -> inclusive scan -> cursor
    __shared__ unsigned lbase[BPB];
    __shared__ unsigned gbse[BPB];

    const int blk = blockIdx.x;
    const int bl  = blk >> 7;          // round-local batch (P1B=128 blocks each)
    const int sub = blk & (P1B - 1);
    const int tid = threadIdx.x;
    scn[tid] = 0;
    __syncthreads();

    const size_t pb_g = (size_t)(b0 + bl) * HWK + (size_t)sub * PXB;
    const i4v* xq = (const i4v*)xy_raw + pb_g / 2;     // 2 px per 16B
    const f2v* dq = (const f2v*)depth  + pb_g / 2;     // 2 px per 8B

    unsigned pk[PPT]; float dd[PPT];
#pragma unroll
    for (int j = 0; j < PPT / 2; ++j) {
        const i4v q = __builtin_nontemporal_load(&xq[j * P1T + tid]);
        const f2v d = __builtin_nontemporal_load(&dq[j * P1T + tid]);
        pk[2 * j]     = (unsigned)q.x | ((unsigned)q.y << 11);
        pk[2 * j + 1] = (unsigned)q.z | ((unsigned)q.w << 11);
        dd[2 * j] = d.x; dd[2 * j + 1] = d.y;
        atomicAdd(&scn[((q.y >> TSH) << 5) | (q.x >> TSH)], 1u);
        atomicAdd(&scn[((q.w >> TSH) << 5) | (q.z >> TSH)], 1u);
    }
    __syncthreads();

    const unsigned creg = scn[tid];
    for (int ofs = 1; ofs < BPB; ofs <<= 1) {          // Hillis-Steele scan
        const unsigned u = (tid >= ofs) ? scn[tid - ofs] : 0u;
        __syncthreads();
        scn[tid] += u;
        __syncthreads();
    }
    const unsigned lb = scn[tid] - creg;
    lbase[tid] = lb;
    gbse[tid]  = atomicAdd(&gcur[(b0 + bl) * BPB + tid], (creg + 7u) & ~7u);
    scn[tid]   = lb;                   // scatter cursor
    __syncthreads();

#pragma unroll
    for (int j = 0; j < PPT / 2; ++j) {
#pragma unroll
        for (int e = 0; e < 2; ++e) {
            const unsigned w = pk[2 * j + e];
            const int x = (int)(w & 0x7FFu), y = (int)(w >> 11);
            const int bn = ((y >> TSH) << 5) | (x >> TSH);
            const unsigned r = atomicAdd(&scn[bn], 1u);
            const unsigned il = (unsigned)(sub * PXB + (j * P1T + tid) * 2 + e);
            u2v rec;
            rec.x = il | ((unsigned)(x & 63) << 20) | ((unsigned)(y & 63) << 26);
            rec.y = __float_as_uint(dd[2 * j + e]);
            srec[r] = rec;
        }
    }
    __syncthreads();

    // burst-write runs: 16 waves x 64 bins; 64B-aligned, fully written
    const int wid = tid >> 6, lane = tid & 63;
    u2v* slb = slab + (size_t)bl * BPB * CAP;
    for (int bn = wid * 64; bn < wid * 64 + 64; ++bn) {
        const int c   = (int)(scn[bn] - lbase[bn]);
        const int len = (c + 7) & ~7;
        const int src = (int)lbase[bn];
        const int gp  = (int)gbse[bn];
        u2v* dst = slb + (size_t)bn * CAP;
        for (int k = lane; k < len; k += 64) {
            const int pos = gp + k;
            if (pos < CAP) {
                u2v r;
                if (k < c) r = srec[src + k];
                else { r.x = 0u; r.y = 0x7F800000u; }  // +inf depth = padding
                dst[pos] = r;
            }
        }
    }
}

// ---------------- Pass 2: LDS tile eval + LDS radix-bucket pairs by il-chunk ----------------
__global__ __launch_bounds__(256, 4) void p2_tile(
    const float* __restrict__ zbuf, const u2v* __restrict__ slab,
    u2v* __restrict__ pairs, const unsigned* __restrict__ gcur,
    unsigned* __restrict__ pcur, int b0)
{
    __shared__ float    zt[STW * STW];             // 17.4 KB
    __shared__ u2v      spair[CAP];                // 13.3 KB chunk-sorted pairs
    __shared__ unsigned cnt[NCH], lb[NCH], cur[NCH], gb[NCH];

    const int gbi = blockIdx.x;                    // round-local bin
    const int tid = threadIdx.x;
    const int bl  = gbi >> 10;
    const int t   = gbi & (BPB - 1);
    const int tx  = t & 31, ty = t >> 5;
    const float* zb = zbuf + (size_t)(b0 + bl) * ((size_t)S_IMG * S_IMG);
    const int x0 = tx * 64 - 1, y0 = ty * 64 - 1;

    if (tid < NCH) cnt[tid] = 0;

    const int n   = min((int)gcur[(b0 + bl) * BPB + t], CAP);
    const int nc  = n - 1;
    const int ncc = max(nc, 0);
    const u2v* sl = slab + (size_t)gbi * CAP;

    u2v Rc[RPT];                                   // preload records early
#pragma unroll
    for (int j = 0; j < RPT; ++j)
        Rc[j] = sl[min(j * 256 + tid, ncc)];

    for (int i = tid; i < STW * STW; i += 256) {
        const int r  = i / STW, c = i - r * STW;
        const int gy = min(max(y0 + r, 0), S_IMG - 1);
        const int gx = min(max(x0 + c, 0), S_IMG - 1);
        zt[i] = zb[(size_t)gy * S_IMG + gx];       // zbuf read ONCE, coalesced
    }
    __syncthreads();                               // also covers cnt init

    float vv[RPT]; unsigned ilv[RPT]; bool val[RPT];
#pragma unroll
    for (int j = 0; j < RPT; ++j) {
        const unsigned w = Rc[j].x;
        val[j] = (j * 256 + tid <= nc) && (Rc[j].y != 0x7F800000u);
        ilv[j] = w & 0xFFFFFu;
        const float a  = __uint_as_float(Rc[j].y) - BIAS;
        const float* p = zt + (int)((w >> 26) & 63u) * STW + (int)((w >> 20) & 63u);
        vv[j] = (sigf(p[0],           a) + sigf(p[1],           a) + sigf(p[2],           a)
               + sigf(p[STW],         a) + sigf(p[STW + 1],     a) + sigf(p[STW + 2],     a)
               + sigf(p[2 * STW],     a) + sigf(p[2 * STW + 1], a) + sigf(p[2 * STW + 2], a))
              * (1.0f / 9.0f);
        if (val[j]) atomicAdd(&cnt[ilv[j] >> CHSH], 1u);
    }
    __syncthreads();

    if (tid == 0) {                                // tiny serial scan (64)
        unsigned s = 0;
        for (int c = 0; c < NCH; ++c) { lb[c] = s; s += cnt[c]; }
    }
    __syncthreads();
    if (tid < NCH) {
        cur[tid] = lb[tid];
        gb[tid]  = atomicAdd(&pcur[(b0 + bl) * NCH + tid], (cnt[tid] + 7u) & ~7u);
    }
    __syncthreads();

#pragma unroll
    for (int j = 0; j < RPT; ++j) {
        if (val[j]) {
            const unsigned c = ilv[j] >> CHSH;
            const unsigned r = atomicAdd(&cur[c], 1u);
            u2v pr; pr.x = ilv[j]; pr.y = __float_as_uint(vv[j]);
            spair[r] = pr;
        }
    }
    __syncthreads();

    // burst-write pair runs: 4 waves x 16 chunks; 64B-aligned, fully written
    const int wid = tid >> 6, lane = tid & 63;
    u2v* pb = pairs + (size_t)bl * NCH * CAP3;
    for (int c = wid * 16; c < wid * 16 + 16; ++c) {
        const int cc  = (int)cnt[c];
        const int len = (cc + 7) & ~7;
        const int src = (int)lb[c];
        const int gp  = (int)gb[c];
        u2v* dst = pb + (size_t)c * CAP3;
        for (int k = lane; k < len; k += 64) {
            const int pos = gp + k;
            if (pos < CAP3) {
                u2v pr;
                if (k < cc) pr = spair[src + k];
                else { pr.x = SENT; pr.y = 0u; }
                dst[pos] = pr;
            }
        }
    }
}

// ---------------- Pass 3: coalesced pair read -> LDS window scatter -> coalesced out ----------------
__global__ __launch_bounds__(1024, 4) void p3_out(
    const u2v* __restrict__ pairs, const unsigned* __restrict__ pcur,
    float* __restrict__ out,
    const float* __restrict__ zbuf, const float* __restrict__ depth,
    const int* __restrict__ xy_raw, int b0)
{
    __shared__ float sd[CHPX];                     // 64 KB window
    const int blk = blockIdx.x;
    const int bl  = blk >> 6;                      // round-local batch
    const int c   = blk & (NCH - 1);
    const int tid = threadIdx.x;

    for (int i = tid; i < CHPX; i += 1024) sd[i] = -1.0f;   // sentinel (vis >= 0)
    __syncthreads();

    const int nlist = min((int)pcur[(b0 + bl) * NCH + c], CAP3);
    const u2v* pl = pairs + ((size_t)bl * NCH + c) * CAP3;
    for (int k = tid; k < nlist; k += 1024) {      // coalesced full-line reads
        const u2v pr = pl[k];
        if (pr.x != SENT) sd[pr.x & (CHPX - 1)] = __uint_as_float(pr.y);
    }
    __syncthreads();

    const size_t pxb = (size_t)(b0 + bl) * HWK + (size_t)c * CHPX;
#pragma unroll
    for (int j = 0; j < 4; ++j) {
        const int idx = (j * 1024 + tid) * 4;
        f4v v = *(const f4v*)(sd + idx);
#pragma unroll
        for (int e = 0; e < 4; ++e) {
            if (v[e] < 0.0f) {                     // overflow-dropped px: exact recompute
                const size_t il = pxb + (size_t)idx + e;
                const int batch = (int)(il >> 20);
                const float a = depth[il] - BIAS;
                const int x = xy_raw[2 * il], y = xy_raw[2 * il + 1];
                const float* zbb = zbuf + (size_t)batch * ((size_t)S_IMG * S_IMG);
                float vr = 0.0f;
                for (int ii = -1; ii <= 1; ++ii) {
                    const int yi = min(max(y + ii, 0), S_IMG - 1);
                    const float* row = zbb + (size_t)yi * S_IMG;
                    for (int jj = -1; jj <= 1; ++jj)
                        vr += sigf(row[min(max(x + jj, 0), S_IMG - 1)], a);
                }
                v[e] = vr * (1.0f / 9.0f);
            }
        }
        __builtin_nontemporal_store(v, (f4v*)(out + pxb) + j * 1024 + tid);
    }
}

// ---------------- fallback: direct kernel ----------------
__global__ __launch_bounds__(256) void pcf_shadow_generic(
    const float* __restrict__ zbuf, const float* __restrict__ depth_z,
    const int2* __restrict__ xy, const int* __restrict__ image_size_p,
    float* __restrict__ out, int total, int zbuf_elems)
{
    const int i = blockIdx.x * blockDim.x + threadIdx.x;
    if (i >= total) return;
    const int S  = *image_size_p;
    const int SS = S * S;
    const int N  = zbuf_elems / SS;
    const int hwk = total / N;
    const int b   = i / hwk;
    const float a = depth_z[i] - BIAS;
    const int2 p  = xy[i];
    const float* base = zbuf + (size_t)b * (size_t)SS;
    float vis = 0.0f;
#pragma unroll
    for (int ii = -1; ii <= 1; ++ii) {
        const int yi = min(max(p.y + ii, 0), S - 1);
        const float* row = base + (size_t)yi * (size_t)S;
#pragma unroll
        for (int jj = -1; jj <= 1; ++jj) {
            const int xi = min(max(p.x + jj, 0), S - 1);
            vis += 1.0f / (1.0f + __expf((a - row[xi]) * SHARPNESS));
        }
    }
    out[i] = vis * (1.0f / 9.0f);
}

extern "C" void kernel_launch(void* const* d_in, const int* in_sizes, int n_in,
                              void* d_out, int out_size, void* d_ws, size_t ws_size,
                              hipStream_t stream) {
    const float* zbuf     = (const float*)d_in[0];
    const float* depth_z  = (const float*)d_in[1];
    const int*   xy_raw   = (const int*)d_in[2];
    const int*   img_size = (const int*)d_in[3];
    float*       out      = (float*)d_out;

    const int zbuf_elems = in_sizes[0];   // N*S*S
    const int total      = in_sizes[1];   // N*H*W*K

    if (zbuf_elems == NBATCH * S_IMG * S_IMG && total == NBATCH * HWK) {
        const size_t slab_pb  = (size_t)BPB * CAP * 8ull;    // 13.63 MB
        const size_t pairs_pb = (size_t)NCH * CAP3 * 8ull;   // 10.88 MB
        const size_t per_b    = slab_pb + pairs_pb;          // 24.51 MB
        const size_t ctr_b    = (size_t)NBATCH * BPB * 4ull  // gcur 32 KB
                              + (size_t)NBATCH * NCH * 4ull; // pcur  2 KB
        int nb = 0;
        if      (ws_size >= 8 * per_b + ctr_b) nb = 8;
        else if (ws_size >= 4 * per_b + ctr_b) nb = 4;
        else if (ws_size >= 2 * per_b + ctr_b) nb = 2;       // 49.06 MB <= proven 50.3
        else if (ws_size >= 1 * per_b + ctr_b) nb = 1;

        if (nb) {
            u2v*      slab  = (u2v*)d_ws;
            u2v*      pairs = (u2v*)((char*)d_ws + (size_t)nb * slab_pb);
            unsigned* gcur  = (unsigned*)((char*)d_ws + (size_t)nb * per_b);
            unsigned* pcur  = gcur + (size_t)NBATCH * BPB;
            hipMemsetAsync(gcur, 0, ctr_b, stream);          // once, all batches
            for (int b0 = 0; b0 < NBATCH; b0 += nb) {
                p1_bin <<<nb * P1B, P1T,  0, stream>>>(xy_raw, depth_z, slab, gcur, b0);
                p2_tile<<<nb * BPB, 256,  0, stream>>>(zbuf, slab, pairs, gcur, pcur, b0);
                p3_out <<<nb * NCH, 1024, 0, stream>>>(pairs, pcur, out,
                                                       zbuf, depth_z, xy_raw, b0);
            }
            return;
        }
    }
    const int block = 256;
    const int grid  = (total + block - 1) / block;
    pcf_shadow_generic<<<grid, block, 0, stream>>>(zbuf, depth_z, (const int2*)xy_raw,
                                                   img_size, out, total, zbuf_elems);
}